// Round 2
// baseline (816.201 us; speedup 1.0000x reference)
//
#include <hip/hip_runtime.h>

#define B_SZ  1024
#define N_SEQ 512
#define D_INP 30
#define H     64
#define G4    256   // 4*H
#define ROWS  2
#define TCH   16                 // timesteps of x staged per chunk
#define NCH   (N_SEQ / TCH)      // 32 chunks

// Pin a float in a VGPR: forbids rematerialization / spill of loaded weights.
#define PIN(v)  asm volatile("" : "+v"(v))
#define PIN4(f) do { PIN((f).x); PIN((f).y); PIN((f).z); PIN((f).w); } while (0)

__device__ __forceinline__ float sigmoid_f(float x) {
  return 1.0f / (1.0f + __expf(-x));
}
__device__ __forceinline__ float tanh_f(float x) {
  return 1.0f - 2.0f / (1.0f + __expf(2.0f * x));
}

// ---------------------------------------------------------------------------
// Kernel A: fold FC into the input-side gate GEMM.
// ---------------------------------------------------------------------------
__global__ __launch_bounds__(256) void prep_kernel(
    const float* __restrict__ W_fc, const float* __restrict__ b_fc,
    const float* __restrict__ W_ih, const float* __restrict__ b_ih,
    const float* __restrict__ b_hh,
    float* __restrict__ wsW, float* __restrict__ wsB) {
  __shared__ float fc[H * D_INP];
  __shared__ float bfc[H];
  const int u = threadIdx.x;
  for (int i = u; i < H * D_INP; i += 256) fc[i] = W_fc[i];
  if (u < H) bfc[u] = b_fc[u];
  __syncthreads();

  float wih[H];
#pragma unroll
  for (int i = 0; i < H; ++i) wih[i] = W_ih[u * H + i];

  for (int k = 0; k < D_INP; ++k) {
    float s = 0.f;
#pragma unroll
    for (int i = 0; i < H; ++i) s = fmaf(wih[i], fc[i * D_INP + k], s);
    wsW[u * 32 + k] = s;
  }
  wsW[u * 32 + 30] = 0.f;
  wsW[u * 32 + 31] = 0.f;

  float bb = b_ih[u] + b_hh[u];
#pragma unroll
  for (int i = 0; i < H; ++i) bb = fmaf(wih[i], bfc[i], bb);
  wsB[u] = bb;
}

// ---------------------------------------------------------------------------
// Kernel B: fused LSTM + logits + softmax. 512 blocks x 256 threads,
// 2 batch rows per block. Thread u owns gate-unit u; its W_hh row (64 f32)
// and W_comb row (32 f32 padded) are PINNED in VGPRs.
// ---------------------------------------------------------------------------
__global__ __launch_bounds__(256, 2) void lstm_kernel(
    const float* __restrict__ x, const float* __restrict__ W_hh,
    const float* __restrict__ wsW, const float* __restrict__ wsB,
    const float* __restrict__ W_last, float* __restrict__ out) {
  __shared__ __align__(16) float h_lds[ROWS][H];
  __shared__ float gates[ROWS][G4];
  __shared__ __align__(16) float xs[ROWS][TCH][32];
  __shared__ float logits[ROWS][N_SEQ];

  const int u = threadIdx.x;
  const int b0 = blockIdx.x * ROWS;

  // ---- per-thread weights, pinned in registers ----
  float4 whh[16];
  {
    const float4* g = (const float4*)(W_hh + u * H);
#pragma unroll
    for (int q = 0; q < 16; ++q) { whh[q] = g[q]; PIN4(whh[q]); }
  }
  float4 wcb[8];
  {
    const float4* g = (const float4*)(wsW + u * 32);
#pragma unroll
    for (int q = 0; q < 8; ++q) { wcb[q] = g[q]; PIN4(wcb[q]); }
  }
  const float bcu = wsB[u];

  float wl = 0.f;
  if (u < ROWS * H) wl = W_last[u & (H - 1)];
  float c_reg = 0.f;
  if (u < ROWS * H) h_lds[u >> 6][u & 63] = 0.f;

  // ---- x chunk prefetch helpers ----
  float pf[4];
  auto load_chunk = [&](int tc, float* p) {
#pragma unroll
    for (int q = 0; q < 4; ++q) {
      int i = u + q * 256;
      int r = i >> 9, rem = i & 511;
      int tt = rem >> 5, k = rem & 31;
      float v = 0.f;
      if (k < D_INP)
        v = x[((size_t)(b0 + r) * N_SEQ + (size_t)(tc * TCH + tt)) * D_INP + k];
      p[q] = v;
    }
  };
  auto store_chunk = [&](const float* p) {
#pragma unroll
    for (int q = 0; q < 4; ++q) {
      int i = u + q * 256;
      int r = i >> 9, rem = i & 511;
      int tt = rem >> 5, k = rem & 31;
      xs[r][tt][k] = p[q];
    }
  };

  load_chunk(0, pf);
  store_chunk(pf);
  __syncthreads();

  const bool isg = (u >= 2 * H) && (u < 3 * H);  // wave 2 => tanh gate

  for (int tc = 0; tc < NCH; ++tc) {
    float pfn[4];
    if (tc + 1 < NCH) load_chunk(tc + 1, pfn);

    for (int tt = 0; tt < TCH; ++tt) {
      float acc0 = bcu, acc1 = bcu;
      // grouped: 4 float4-pairs of h live at a time -> bounded pressure
#pragma unroll
      for (int g = 0; g < 4; ++g) {
        float4 ha[4], hb[4];
#pragma unroll
        for (int q = 0; q < 4; ++q) {
          ha[q] = *(const float4*)&h_lds[0][(g * 4 + q) * 4];
          hb[q] = *(const float4*)&h_lds[1][(g * 4 + q) * 4];
        }
#pragma unroll
        for (int q = 0; q < 4; ++q) {
          float4 w = whh[g * 4 + q];
          acc0 = fmaf(w.x, ha[q].x, acc0); acc0 = fmaf(w.y, ha[q].y, acc0);
          acc0 = fmaf(w.z, ha[q].z, acc0); acc0 = fmaf(w.w, ha[q].w, acc0);
          acc1 = fmaf(w.x, hb[q].x, acc1); acc1 = fmaf(w.y, hb[q].y, acc1);
          acc1 = fmaf(w.z, hb[q].z, acc1); acc1 = fmaf(w.w, hb[q].w, acc1);
        }
      }
#pragma unroll
      for (int g = 0; g < 2; ++g) {
        float4 xa[4], xb[4];
#pragma unroll
        for (int q = 0; q < 4; ++q) {
          xa[q] = *(const float4*)&xs[0][tt][(g * 4 + q) * 4];
          xb[q] = *(const float4*)&xs[1][tt][(g * 4 + q) * 4];
        }
#pragma unroll
        for (int q = 0; q < 4; ++q) {
          float4 w = wcb[g * 4 + q];
          acc0 = fmaf(w.x, xa[q].x, acc0); acc0 = fmaf(w.y, xa[q].y, acc0);
          acc0 = fmaf(w.z, xa[q].z, acc0); acc0 = fmaf(w.w, xa[q].w, acc0);
          acc1 = fmaf(w.x, xb[q].x, acc1); acc1 = fmaf(w.y, xb[q].y, acc1);
          acc1 = fmaf(w.z, xb[q].z, acc1); acc1 = fmaf(w.w, xb[q].w, acc1);
        }
      }

      float g0, g1;
      if (isg) { g0 = tanh_f(acc0); g1 = tanh_f(acc1); }
      else     { g0 = sigmoid_f(acc0); g1 = sigmoid_f(acc1); }
      gates[0][u] = g0;
      gates[1][u] = g1;
      __syncthreads();

      if (u < ROWS * H) {
        const int r = u >> 6, j = u & 63;
        float gi = gates[r][j];
        float gf = gates[r][H + j];
        float gg = gates[r][2 * H + j];
        float go = gates[r][3 * H + j];
        c_reg = fmaf(gf, c_reg, gi * gg);
        float h = go * tanh_f(c_reg);
        h_lds[r][j] = h;
        float wsum = h * wl;   // b_last cancels in softmax
#pragma unroll
        for (int m = 32; m >= 1; m >>= 1) wsum += __shfl_xor(wsum, m, 64);
        if (j == 0) logits[r][tc * TCH + tt] = wsum;
      }
      __syncthreads();
    }

    if (tc + 1 < NCH) {
      store_chunk(pfn);
      __syncthreads();
    }
  }

  // ---- softmax over time, one wave per batch row ----
  __syncthreads();
  if (u < ROWS * H) {
    const int r = u >> 6, j = u & 63;
    float l[8], vmax = -3.0e38f;
#pragma unroll
    for (int s = 0; s < 8; ++s) {
      l[s] = logits[r][j + 64 * s];
      vmax = fmaxf(vmax, l[s]);
    }
#pragma unroll
    for (int m = 32; m >= 1; m >>= 1) vmax = fmaxf(vmax, __shfl_xor(vmax, m, 64));
    float e[8], sum = 0.f;
#pragma unroll
    for (int s = 0; s < 8; ++s) { e[s] = __expf(l[s] - vmax); sum += e[s]; }
#pragma unroll
    for (int m = 32; m >= 1; m >>= 1) sum += __shfl_xor(sum, m, 64);
    float inv = 1.0f / sum;
#pragma unroll
    for (int s = 0; s < 8; ++s)
      out[(size_t)(b0 + r) * N_SEQ + j + 64 * s] = e[s] * inv;
  }
}

// ---------------------------------------------------------------------------
extern "C" void kernel_launch(void* const* d_in, const int* in_sizes, int n_in,
                              void* d_out, int out_size, void* d_ws, size_t ws_size,
                              hipStream_t stream) {
  const float* x      = (const float*)d_in[0];
  const float* W_fc   = (const float*)d_in[1];
  const float* b_fc   = (const float*)d_in[2];
  const float* W_ih   = (const float*)d_in[3];
  const float* W_hh   = (const float*)d_in[4];
  const float* b_ih   = (const float*)d_in[5];
  const float* b_hh   = (const float*)d_in[6];
  const float* W_last = (const float*)d_in[7];
  // d_in[8] = b_last: cancels in softmax.

  float* out = (float*)d_out;
  float* wsW = (float*)d_ws;        // 256*32 floats
  float* wsB = wsW + G4 * 32;       // 256 floats

  prep_kernel<<<1, 256, 0, stream>>>(W_fc, b_fc, W_ih, b_ih, b_hh, wsW, wsB);
  lstm_kernel<<<B_SZ / ROWS, 256, 0, stream>>>(x, W_hh, wsW, wsB, W_last, out);
}

// Round 3
// 708.983 us; speedup vs baseline: 1.1512x; 1.1512x over previous
//
#include <hip/hip_runtime.h>

#define B_SZ  1024
#define NSEQ  512
#define D_INP 30
#define H     64
#define MB    16      // batch rows per block
#define TCH   4       // x timesteps staged per chunk

typedef short s16x8 __attribute__((ext_vector_type(8)));
typedef float f32x4 __attribute__((ext_vector_type(4)));

__device__ __forceinline__ float sigf(float v)  { return 1.0f / (1.0f + __expf(-v)); }
__device__ __forceinline__ float tanhx(float v) { return 1.0f - 2.0f / (1.0f + __expf(2.0f * v)); }

__device__ __forceinline__ f32x4 mfma16(s16x8 a, s16x8 b, f32x4 c) {
  return __builtin_amdgcn_mfma_f32_16x16x32_bf16(a, b, c, 0, 0, 0);
}

// split 8 fp32 -> bf16 hi (truncate) + bf16 lo (residual, truncate)
__device__ __forceinline__ void split8(const float* f, s16x8& hi, s16x8& lo) {
#pragma unroll
  for (int i = 0; i < 8; ++i) {
    unsigned ub = __float_as_uint(f[i]);
    hi[i] = (short)(ub >> 16);
    float hf = __uint_as_float(ub & 0xFFFF0000u);
    float lf = f[i] - hf;
    lo[i] = (short)(__float_as_uint(lf) >> 16);
  }
}

// ---------------------------------------------------------------------------
// Kernel A: fold FC into the input-side gate GEMM (fp32, unchanged).
// wsW[u][k] (stride 32, zero-padded k=30,31), wsB[u] = combined bias.
// ---------------------------------------------------------------------------
__global__ __launch_bounds__(256) void prep_kernel(
    const float* __restrict__ W_fc, const float* __restrict__ b_fc,
    const float* __restrict__ W_ih, const float* __restrict__ b_ih,
    const float* __restrict__ b_hh,
    float* __restrict__ wsW, float* __restrict__ wsB) {
  __shared__ float fc[H * D_INP];
  __shared__ float bfc[H];
  const int u = threadIdx.x;
  for (int i = u; i < H * D_INP; i += 256) fc[i] = W_fc[i];
  if (u < H) bfc[u] = b_fc[u];
  __syncthreads();

  float wih[H];
#pragma unroll
  for (int i = 0; i < H; ++i) wih[i] = W_ih[u * H + i];

  for (int k = 0; k < D_INP; ++k) {
    float s = 0.f;
#pragma unroll
    for (int i = 0; i < H; ++i) s = fmaf(wih[i], fc[i * D_INP + k], s);
    wsW[u * 32 + k] = s;
  }
  wsW[u * 32 + 30] = 0.f;
  wsW[u * 32 + 31] = 0.f;

  float bb = b_ih[u] + b_hh[u];
#pragma unroll
  for (int i = 0; i < H; ++i) bb = fmaf(wih[i], bfc[i], bb);
  wsB[u] = bb;
}

// ---------------------------------------------------------------------------
// Kernel B: MFMA LSTM. 64 blocks x 256 threads; block owns 16 batch rows.
// Wave w owns N-tiles {w, w+4, w+8, w+12} -> gate g = tile index within wave,
// so i/f/g/o of hidden elem j = 16w+(lane&15) are co-located per lane.
// ---------------------------------------------------------------------------
__global__ __launch_bounds__(256, 1) void lstm_mfma(
    const float* __restrict__ x, const float* __restrict__ W_hh,
    const float* __restrict__ wsW, const float* __restrict__ wsB,
    const float* __restrict__ W_last, float* __restrict__ out) {

  __shared__ short xa[2][TCH][2][64][8];       // x A-frags bf16 hi/lo, 16 KB
  __shared__ float hbuf[2][MB][68];            // h double-buffer, pad 68, 8.7 KB
  __shared__ float logitsT[NSEQ + 1][MB];      // logit_{t-1} at slot t, 32.8 KB

  const int u   = threadIdx.x;
  const int w   = u >> 6;       // wave id
  const int l   = u & 63;       // lane
  const int low = l & 15;
  const int q   = l >> 4;
  const int b0  = blockIdx.x * MB;

  // ---- B-fragments (weights), hi/lo split, in registers ----
  s16x8 whh_h[4][2], whh_l[4][2], wcb_h[4], wcb_l[4], wl_h[2], wl_l[2];
  float biasv[4];
#pragma unroll
  for (int g = 0; g < 4; ++g) {
    const int n = 64 * g + 16 * w + low;   // unit owned at this lane/tile
#pragma unroll
    for (int kt = 0; kt < 2; ++kt) {
      float tmp[8];
      const float* p = W_hh + n * H + kt * 32 + q * 8;
#pragma unroll
      for (int j = 0; j < 8; ++j) tmp[j] = p[j];
      split8(tmp, whh_h[g][kt], whh_l[g][kt]);
    }
    {
      float tmp[8];
      const float* p = wsW + n * 32 + q * 8;
#pragma unroll
      for (int j = 0; j < 8; ++j) tmp[j] = p[j];
      split8(tmp, wcb_h[g], wcb_l[g]);
    }
    biasv[g] = wsB[n];
  }
#pragma unroll
  for (int kt = 0; kt < 2; ++kt) {
    float tmp[8];
#pragma unroll
    for (int j = 0; j < 8; ++j)
      tmp[j] = (low == 0) ? W_last[kt * 32 + q * 8 + j] : 0.0f;
    split8(tmp, wl_h[kt], wl_l[kt]);
  }

  // zero h buffers
  for (int i = u; i < 2 * MB * 68; i += 256) ((float*)hbuf)[i] = 0.f;

  // ---- x staging: thread covers (row=low within frag, k=q*8 + 2w, +1) ----
  const int sk = q * 8 + (w << 1);
  const bool svalid = (sk < D_INP);
  const float* xbase = x + (size_t)(b0 + low) * NSEQ * D_INP + sk;

  float2 pf[TCH];
  auto stage_load = [&](int t0) {
#pragma unroll
    for (int s = 0; s < TCH; ++s)
      pf[s] = svalid ? *(const float2*)(xbase + (size_t)(t0 + s) * D_INP)
                     : make_float2(0.f, 0.f);
  };
  auto stage_write = [&](int buf) {
#pragma unroll
    for (int s = 0; s < TCH; ++s) {
      unsigned u0 = __float_as_uint(pf[s].x);
      unsigned u1 = __float_as_uint(pf[s].y);
      unsigned hw = (u1 & 0xFFFF0000u) | (u0 >> 16);
      float l0 = pf[s].x - __uint_as_float(u0 & 0xFFFF0000u);
      float l1 = pf[s].y - __uint_as_float(u1 & 0xFFFF0000u);
      unsigned lw = (__float_as_uint(l1) & 0xFFFF0000u) | (__float_as_uint(l0) >> 16);
      *(unsigned*)&xa[buf][s][0][l][w << 1] = hw;
      *(unsigned*)&xa[buf][s][1][l][w << 1] = lw;
    }
  };

  stage_load(0);
  stage_write(0);
  __syncthreads();

  f32x4 c4 = {0.f, 0.f, 0.f, 0.f};
  const int jcol = 16 * w + low;

  for (int t = 0; t < NSEQ; ++t) {
    const int tt = t & (TCH - 1);
    const int cb = (t >> 2) & 1;
    if (tt == 0 && t + TCH < NSEQ) stage_load(t + TCH);

    // x A-frags (pre-split bf16)
    s16x8 xah = *(const s16x8*)&xa[cb][tt][0][l][0];
    s16x8 xal = *(const s16x8*)&xa[cb][tt][1][l][0];

    // h A-frags: fp32 read + in-register split
    const float* hp = &hbuf[(t + 1) & 1][low][0];
    s16x8 ah[2], al[2];
#pragma unroll
    for (int kt = 0; kt < 2; ++kt) {
      float tmp[8];
      const float* p = hp + kt * 32 + q * 8;
#pragma unroll
      for (int j = 0; j < 8; ++j) tmp[j] = p[j];
      split8(tmp, ah[kt], al[kt]);
    }

    f32x4 acc[4];
#pragma unroll
    for (int g = 0; g < 4; ++g) {
      f32x4 a = {biasv[g], biasv[g], biasv[g], biasv[g]};
      a = mfma16(xah, wcb_h[g], a);
      a = mfma16(xah, wcb_l[g], a);
      a = mfma16(xal, wcb_h[g], a);
#pragma unroll
      for (int kt = 0; kt < 2; ++kt) {
        a = mfma16(ah[kt], whh_h[g][kt], a);
        a = mfma16(ah[kt], whh_l[g][kt], a);
        a = mfma16(al[kt], whh_h[g][kt], a);
      }
      acc[g] = a;
    }

    // logit_{t-1} = h_{t-1} . W_last  (extra N-tile, wave 0 only)
    if (w == 0) {
      f32x4 aL = {0.f, 0.f, 0.f, 0.f};
#pragma unroll
      for (int kt = 0; kt < 2; ++kt) {
        aL = mfma16(ah[kt], wl_h[kt], aL);
        aL = mfma16(ah[kt], wl_l[kt], aL);
        aL = mfma16(al[kt], wl_h[kt], aL);
      }
      if (low == 0) *(f32x4*)&logitsT[t][q * 4] = aL;
    }

    // per-lane LSTM cell update: rows m = q*4+r, hidden elem jcol
#pragma unroll
    for (int r = 0; r < 4; ++r) {
      float gi = sigf(acc[0][r]);
      float gf = sigf(acc[1][r]);
      float gg = tanhx(acc[2][r]);
      float go = sigf(acc[3][r]);
      float cc = fmaf(gf, c4[r], gi * gg);
      c4[r] = cc;
      float h = go * tanhx(cc);
      hbuf[t & 1][q * 4 + r][jcol] = h;
    }

    if (tt == 2 && t + 2 < NSEQ) stage_write(cb ^ 1);
    __syncthreads();
  }

  // final logit from h_511 (in hbuf[1])
  if (w == 0) {
    const float* hp = &hbuf[1][low][0];
    s16x8 ah[2], al[2];
#pragma unroll
    for (int kt = 0; kt < 2; ++kt) {
      float tmp[8];
      const float* p = hp + kt * 32 + q * 8;
#pragma unroll
      for (int j = 0; j < 8; ++j) tmp[j] = p[j];
      split8(tmp, ah[kt], al[kt]);
    }
    f32x4 aL = {0.f, 0.f, 0.f, 0.f};
#pragma unroll
    for (int kt = 0; kt < 2; ++kt) {
      aL = mfma16(ah[kt], wl_h[kt], aL);
      aL = mfma16(ah[kt], wl_l[kt], aL);
      aL = mfma16(al[kt], wl_h[kt], aL);
    }
    if (low == 0) *(f32x4*)&logitsT[NSEQ][q * 4] = aL;
  }
  __syncthreads();

  // ---- softmax over time: row m = u>>4, 16 lanes cover t' = (u&15) + 16s ----
  {
    const int m = u >> 4, li = u & 15;
    float lv[32];
    float mx = -3.0e38f;
#pragma unroll
    for (int s = 0; s < 32; ++s) {
      lv[s] = logitsT[1 + li + 16 * s][m];
      mx = fmaxf(mx, lv[s]);
    }
#pragma unroll
    for (int d = 1; d < 16; d <<= 1) mx = fmaxf(mx, __shfl_xor(mx, d, 16));
    float sum = 0.f;
#pragma unroll
    for (int s = 0; s < 32; ++s) { lv[s] = __expf(lv[s] - mx); sum += lv[s]; }
#pragma unroll
    for (int d = 1; d < 16; d <<= 1) sum += __shfl_xor(sum, d, 16);
    float inv = 1.0f / sum;
#pragma unroll
    for (int s = 0; s < 32; ++s)
      out[(size_t)(b0 + m) * NSEQ + li + 16 * s] = lv[s] * inv;
  }
}

// ---------------------------------------------------------------------------
extern "C" void kernel_launch(void* const* d_in, const int* in_sizes, int n_in,
                              void* d_out, int out_size, void* d_ws, size_t ws_size,
                              hipStream_t stream) {
  const float* x      = (const float*)d_in[0];
  const float* W_fc   = (const float*)d_in[1];
  const float* b_fc   = (const float*)d_in[2];
  const float* W_ih   = (const float*)d_in[3];
  const float* W_hh   = (const float*)d_in[4];
  const float* b_ih   = (const float*)d_in[5];
  const float* b_hh   = (const float*)d_in[6];
  const float* W_last = (const float*)d_in[7];
  // d_in[8] = b_last: cancels in softmax.

  float* out = (float*)d_out;
  float* wsW = (float*)d_ws;          // 256*32 floats
  float* wsB = wsW + 256 * 32;        // 256 floats

  prep_kernel<<<1, 256, 0, stream>>>(W_fc, b_fc, W_ih, b_ih, b_hh, wsW, wsB);
  lstm_mfma<<<B_SZ / MB, 256, 0, stream>>>(x, W_hh, wsW, wsB, W_last, out);
}

// Round 4
// 573.587 us; speedup vs baseline: 1.4230x; 1.2361x over previous
//
#include <hip/hip_runtime.h>

#define B_SZ  1024
#define NSEQ  512
#define D_INP 30
#define H     64
#define MB    16      // batch rows per block
#define TCH   8       // x timesteps staged per chunk

typedef short s16x8 __attribute__((ext_vector_type(8)));
typedef float f32x4 __attribute__((ext_vector_type(4)));

__device__ __forceinline__ float rcp_f(float v) { return __builtin_amdgcn_rcpf(v); }
__device__ __forceinline__ float sigf(float v)  { return rcp_f(1.0f + __expf(-v)); }
__device__ __forceinline__ float tanhx(float v) { return 1.0f - 2.0f * rcp_f(1.0f + __expf(2.0f * v)); }

__device__ __forceinline__ f32x4 mfma16(s16x8 a, s16x8 b, f32x4 c) {
  return __builtin_amdgcn_mfma_f32_16x16x32_bf16(a, b, c, 0, 0, 0);
}

// split 8 fp32 -> bf16 hi (truncate) + bf16 lo (residual, truncate)
__device__ __forceinline__ void split8(const float* f, s16x8& hi, s16x8& lo) {
#pragma unroll
  for (int i = 0; i < 8; ++i) {
    unsigned ub = __float_as_uint(f[i]);
    hi[i] = (short)(ub >> 16);
    float hf = __uint_as_float(ub & 0xFFFF0000u);
    float lf = f[i] - hf;
    lo[i] = (short)(__float_as_uint(lf) >> 16);
  }
}

// ---------------------------------------------------------------------------
// Kernel A: fold FC into the input-side gate GEMM (fp32).
// ---------------------------------------------------------------------------
__global__ __launch_bounds__(256) void prep_kernel(
    const float* __restrict__ W_fc, const float* __restrict__ b_fc,
    const float* __restrict__ W_ih, const float* __restrict__ b_ih,
    const float* __restrict__ b_hh,
    float* __restrict__ wsW, float* __restrict__ wsB) {
  __shared__ float fc[H * D_INP];
  __shared__ float bfc[H];
  const int u = threadIdx.x;
  for (int i = u; i < H * D_INP; i += 256) fc[i] = W_fc[i];
  if (u < H) bfc[u] = b_fc[u];
  __syncthreads();

  float wih[H];
#pragma unroll
  for (int i = 0; i < H; ++i) wih[i] = W_ih[u * H + i];

  for (int k = 0; k < D_INP; ++k) {
    float s = 0.f;
#pragma unroll
    for (int i = 0; i < H; ++i) s = fmaf(wih[i], fc[i * D_INP + k], s);
    wsW[u * 32 + k] = s;
  }
  wsW[u * 32 + 30] = 0.f;
  wsW[u * 32 + 31] = 0.f;

  float bb = b_ih[u] + b_hh[u];
#pragma unroll
  for (int i = 0; i < H; ++i) bb = fmaf(wih[i], bfc[i], bb);
  wsB[u] = bb;
}

// ---------------------------------------------------------------------------
// Kernel B: MFMA LSTM. 64 blocks x 256 threads; block owns 16 batch rows.
// Wave w owns N-tiles {w, w+4, w+8, w+12} -> all 4 gates of hidden elem
// j = 16w+low co-located per lane. h stored in LDS as packed (bf16hi|bf16lo)
// u32 by the producer; consumers rebuild planes with v_perm.
// ---------------------------------------------------------------------------
__global__ __launch_bounds__(256, 1) void lstm_mfma(
    const float* __restrict__ x, const float* __restrict__ W_hh,
    const float* __restrict__ wsW, const float* __restrict__ wsB,
    const float* __restrict__ W_last, float* __restrict__ out) {

  __shared__ short xa[2][TCH][2][64][8];       // x A-frags bf16 hi/lo, 32 KB
  __shared__ unsigned hb[2][MB][68];           // packed h double-buffer, 8.7 KB
  __shared__ float logitsT[NSEQ + 1][MB];      // logit of h_{t-1} at slot t

  const int u   = threadIdx.x;
  const int w   = u >> 6;       // wave id
  const int l   = u & 63;       // lane
  const int low = l & 15;
  const int q   = l >> 4;
  const int b0  = blockIdx.x * MB;

  // ---- B-fragments (weights), hi/lo split, in registers ----
  s16x8 whh_h[4][2], whh_l[4][2], wcb_h[4], wcb_l[4], wl_h[2], wl_l[2];
  float biasv[4];
#pragma unroll
  for (int g = 0; g < 4; ++g) {
    const int n = 64 * g + 16 * w + low;
#pragma unroll
    for (int kt = 0; kt < 2; ++kt) {
      float tmp[8];
      const float* p = W_hh + n * H + kt * 32 + q * 8;
#pragma unroll
      for (int j = 0; j < 8; ++j) tmp[j] = p[j];
      split8(tmp, whh_h[g][kt], whh_l[g][kt]);
    }
    {
      float tmp[8];
      const float* p = wsW + n * 32 + q * 8;
#pragma unroll
      for (int j = 0; j < 8; ++j) tmp[j] = p[j];
      split8(tmp, wcb_h[g], wcb_l[g]);
    }
    biasv[g] = wsB[n];
  }
#pragma unroll
  for (int kt = 0; kt < 2; ++kt) {
    float tmp[8];
#pragma unroll
    for (int j = 0; j < 8; ++j)
      tmp[j] = (low == 0) ? W_last[kt * 32 + q * 8 + j] : 0.0f;
    split8(tmp, wl_h[kt], wl_l[kt]);
  }

  // zero packed-h buffers (pack(0) == 0)
  for (int i = u; i < 2 * MB * 68; i += 256) ((unsigned*)hb)[i] = 0u;

  // ---- x staging (verified layout): thread covers (row=low, k=q*8+2w) ----
  const int sk = q * 8 + (w << 1);
  const bool svalid = (sk < D_INP);
  const float* xbase = x + (size_t)(b0 + low) * NSEQ * D_INP + sk;

  float2 pf[TCH];
  auto stage_load = [&](int t0) {
#pragma unroll
    for (int s = 0; s < TCH; ++s)
      pf[s] = svalid ? *(const float2*)(xbase + (size_t)(t0 + s) * D_INP)
                     : make_float2(0.f, 0.f);
  };
  auto stage_write = [&](int buf) {
#pragma unroll
    for (int s = 0; s < TCH; ++s) {
      unsigned u0 = __float_as_uint(pf[s].x);
      unsigned u1 = __float_as_uint(pf[s].y);
      unsigned hw = (u1 & 0xFFFF0000u) | (u0 >> 16);
      float l0 = pf[s].x - __uint_as_float(u0 & 0xFFFF0000u);
      float l1 = pf[s].y - __uint_as_float(u1 & 0xFFFF0000u);
      unsigned lw = (__float_as_uint(l1) & 0xFFFF0000u) | (__float_as_uint(l0) >> 16);
      *(unsigned*)&xa[buf][s][0][l][w << 1] = hw;
      *(unsigned*)&xa[buf][s][1][l][w << 1] = lw;
    }
  };

  stage_load(0);
  stage_write(0);
  __syncthreads();

  f32x4 c4 = {0.f, 0.f, 0.f, 0.f};
  const int jcol = 16 * w + low;

  for (int t = 0; t < NSEQ; ++t) {
    const int tt = t & (TCH - 1);
    const int cb = (t / TCH) & 1;
    if (tt == 0 && t + TCH < NSEQ) stage_load(t + TCH);

    // x A-frags (pre-split bf16, staged)
    s16x8 xah = *(const s16x8*)&xa[cb][tt][0][l][0];
    s16x8 xal = *(const s16x8*)&xa[cb][tt][1][l][0];

    // h A-frags: packed u32 read + v_perm unpack (hi|lo)
    const unsigned* hp = &hb[(t + 1) & 1][low][0];
    s16x8 ah[2], al[2];
#pragma unroll
    for (int kt = 0; kt < 2; ++kt) {
      unsigned e[8];
      *(uint4*)&e[0] = *(const uint4*)(hp + kt * 32 + q * 8);
      *(uint4*)&e[4] = *(const uint4*)(hp + kt * 32 + q * 8 + 4);
      unsigned hi4[4], lo4[4];
#pragma unroll
      for (int p = 0; p < 4; ++p) {
        hi4[p] = __builtin_amdgcn_perm(e[2 * p + 1], e[2 * p], 0x07060302u);
        lo4[p] = __builtin_amdgcn_perm(e[2 * p + 1], e[2 * p], 0x05040100u);
      }
      ah[kt] = *(const s16x8*)hi4;
      al[kt] = *(const s16x8*)lo4;
    }

    // 8 independent MFMA chains (depth <= 6), add at end
    f32x4 acc[4];
#pragma unroll
    for (int g = 0; g < 4; ++g) {
      f32x4 a = {biasv[g], biasv[g], biasv[g], biasv[g]};
      a = mfma16(xah, wcb_h[g], a);
      a = mfma16(ah[0], whh_h[g][0], a);
      a = mfma16(ah[1], whh_h[g][1], a);
      f32x4 b = {0.f, 0.f, 0.f, 0.f};
      b = mfma16(xah, wcb_l[g], b);
      b = mfma16(xal, wcb_h[g], b);
      b = mfma16(ah[0], whh_l[g][0], b);
      b = mfma16(al[0], whh_h[g][0], b);
      b = mfma16(ah[1], whh_l[g][1], b);
      b = mfma16(al[1], whh_h[g][1], b);
      acc[g] = a + b;
    }

    // logit_{t-1}: rotate the extra N-tile across waves
    if (w == (t & 3)) {
      f32x4 aL = {0.f, 0.f, 0.f, 0.f};
#pragma unroll
      for (int kt = 0; kt < 2; ++kt) {
        aL = mfma16(ah[kt], wl_h[kt], aL);
        aL = mfma16(ah[kt], wl_l[kt], aL);
        aL = mfma16(al[kt], wl_h[kt], aL);
      }
      if (low == 0) *(f32x4*)&logitsT[t][q * 4] = aL;
    }

    // per-lane LSTM cell update; producer-side bf16 split + packed write
#pragma unroll
    for (int r = 0; r < 4; ++r) {
      float gi = sigf(acc[0][r]);
      float gf = sigf(acc[1][r]);
      float gg = tanhx(acc[2][r]);
      float go = sigf(acc[3][r]);
      float cc = fmaf(gf, c4[r], gi * gg);
      c4[r] = cc;
      float h = go * tanhx(cc);
      unsigned uh = __float_as_uint(h);
      float lf = h - __uint_as_float(uh & 0xFFFF0000u);
      unsigned pk = (uh & 0xFFFF0000u) | (__float_as_uint(lf) >> 16);
      hb[t & 1][q * 4 + r][jcol] = pk;
    }

    if (tt == TCH / 2 && t + TCH / 2 < NSEQ) stage_write(cb ^ 1);
    __syncthreads();
  }

  // final logit from h_511 (in hb[1])
  if (w == 0) {
    const unsigned* hp = &hb[1][low][0];
    s16x8 ah[2], al[2];
#pragma unroll
    for (int kt = 0; kt < 2; ++kt) {
      unsigned e[8];
      *(uint4*)&e[0] = *(const uint4*)(hp + kt * 32 + q * 8);
      *(uint4*)&e[4] = *(const uint4*)(hp + kt * 32 + q * 8 + 4);
      unsigned hi4[4], lo4[4];
#pragma unroll
      for (int p = 0; p < 4; ++p) {
        hi4[p] = __builtin_amdgcn_perm(e[2 * p + 1], e[2 * p], 0x07060302u);
        lo4[p] = __builtin_amdgcn_perm(e[2 * p + 1], e[2 * p], 0x05040100u);
      }
      ah[kt] = *(const s16x8*)hi4;
      al[kt] = *(const s16x8*)lo4;
    }
    f32x4 aL = {0.f, 0.f, 0.f, 0.f};
#pragma unroll
    for (int kt = 0; kt < 2; ++kt) {
      aL = mfma16(ah[kt], wl_h[kt], aL);
      aL = mfma16(ah[kt], wl_l[kt], aL);
      aL = mfma16(al[kt], wl_h[kt], aL);
    }
    if (low == 0) *(f32x4*)&logitsT[NSEQ][q * 4] = aL;
  }
  __syncthreads();

  // ---- softmax over time: row m = u>>4, lanes cover t' = (u&15) + 16s ----
  {
    const int m = u >> 4, li = u & 15;
    float lv[32];
    float mx = -3.0e38f;
#pragma unroll
    for (int s = 0; s < 32; ++s) {
      lv[s] = logitsT[1 + li + 16 * s][m];
      mx = fmaxf(mx, lv[s]);
    }
#pragma unroll
    for (int d = 1; d < 16; d <<= 1) mx = fmaxf(mx, __shfl_xor(mx, d, 16));
    float sum = 0.f;
#pragma unroll
    for (int s = 0; s < 32; ++s) { lv[s] = __expf(lv[s] - mx); sum += lv[s]; }
#pragma unroll
    for (int d = 1; d < 16; d <<= 1) sum += __shfl_xor(sum, d, 16);
    float inv = 1.0f / sum;
#pragma unroll
    for (int s = 0; s < 32; ++s)
      out[(size_t)(b0 + m) * NSEQ + li + 16 * s] = lv[s] * inv;
  }
}

// ---------------------------------------------------------------------------
extern "C" void kernel_launch(void* const* d_in, const int* in_sizes, int n_in,
                              void* d_out, int out_size, void* d_ws, size_t ws_size,
                              hipStream_t stream) {
  const float* x      = (const float*)d_in[0];
  const float* W_fc   = (const float*)d_in[1];
  const float* b_fc   = (const float*)d_in[2];
  const float* W_ih   = (const float*)d_in[3];
  const float* W_hh   = (const float*)d_in[4];
  const float* b_ih   = (const float*)d_in[5];
  const float* b_hh   = (const float*)d_in[6];
  const float* W_last = (const float*)d_in[7];
  // d_in[8] = b_last: cancels in softmax.

  float* out = (float*)d_out;
  float* wsW = (float*)d_ws;          // 256*32 floats
  float* wsB = wsW + 256 * 32;        // 256 floats

  prep_kernel<<<1, 256, 0, stream>>>(W_fc, b_fc, W_ih, b_ih, b_hh, wsW, wsB);
  lstm_mfma<<<B_SZ / MB, 256, 0, stream>>>(x, W_hh, wsW, wsB, W_last, out);
}